// Round 7
// baseline (77.859 us; speedup 1.0000x reference)
//
#include <hip/hip_runtime.h>

// CHMM forward-backward, clone-structured deterministic emission (n_clones=8).
// Single cooperative kernel, point-to-point RELAXED agent-scope flag dataflow.
// Waves 1-3 of each block zero-fill that block's 32 output rows with a
// per-block CHANNEL PHASE ROTATION (block b starts 2KiB*b into its region,
// wraps) so the 256 lockstep blocks spread across all HBM channels instead of
// aliasing on the same channel phase (R5/R6: 1.58 TB/s = peak/4). Wave 0 runs
// the chunked scan (group products staged to LDS before the serial product).
// One __syncthreads joins fill+scan (drains fill stores); block scatters its
// gamma windows into its own pre-zeroed rows. Replays value-idempotent.

#define NSTATES 4096
#define NBLK    8
#define LSEQ    8192
#define NSTEPS  8191
#define CHK     32
#define NCH     256
#define NGRP    16
#define GSZ     16

// ws float offsets
#define OFF_P   0u       // [NCH*64]  chunk products, col-major [c*64 + col*8 + row]
#define OFF_G2  16384u   // [NGRP*64] group products, col-major
#define OFF_LLP 17408u   // [NCH]     per-chunk log-lik partials
// ws uint offsets (flags)
#define FLG_F1  17664u   // [NCH]
#define FLG_F2  17920u   // [NGRP]
#define FLG_F3  17936u   // [NCH]
#define MAGIC   0x5A17C0DEu

__device__ __forceinline__ float aload(float* p) {
    return __hip_atomic_load(p, __ATOMIC_RELAXED, __HIP_MEMORY_SCOPE_AGENT);
}
__device__ __forceinline__ void astore(float* p, float v) {
    __hip_atomic_store(p, v, __ATOMIC_RELAXED, __HIP_MEMORY_SCOPE_AGENT);
}
__device__ __forceinline__ unsigned aloadu(unsigned* p) {
    return __hip_atomic_load(p, __ATOMIC_RELAXED, __HIP_MEMORY_SCOPE_AGENT);
}
__device__ __forceinline__ void astoreu(unsigned* p, unsigned v) {
    __hip_atomic_store(p, v, __ATOMIC_RELAXED, __HIP_MEMORY_SCOPE_AGENT);
}
#define VMFENCE()  asm volatile("s_waitcnt vmcnt(0)" ::: "memory")
#define LDSFENCE() asm volatile("s_waitcnt lgkmcnt(0)" ::: "memory")

__device__ __forceinline__ float exp_renorm(float x, float ref) {
    int k = (int)((__float_as_uint(ref) >> 23) & 0xff) - 127;
    return ldexpf(x, -k);
}

__global__ __launch_bounds__(256) void kFB(const float* __restrict__ T,
                                           const float* __restrict__ Pi,
                                           const int* __restrict__ obs,
                                           float* __restrict__ out,
                                           float* __restrict__ ws)
{
    __shared__ float sM[CHK * 64];        // own chunk matrices, col-major/step
    __shared__ float sDuty[GSZ * 64];     // duty group's chunk products (b<16)
    __shared__ float sG2[NGRP * 64];      // staged group products
    __shared__ float sGP[GSZ * 64];       // staged own-group chunk products
    __shared__ float sA[(CHK + 1) * 8];   // alpha history
    __shared__ float sB[(CHK + 1) * 8];   // beta history
    __shared__ int   sObs[CHK];
    unsigned* flg = reinterpret_cast<unsigned*>(ws);
    const int tid = threadIdx.x;
    const int b = blockIdx.x;
    const int g = b >> 4, rIn = b & 15;
    const int t0 = b * CHK;
    const int n = min(CHK, NSTEPS - t0);  // 32; block 255: 31
    float ll0 = 0.f;

    // ---- gather own chunk's 8x8 T-blocks into LDS (all 256 threads) -------
    {
        int dt = tid >> 3, i = tid & 7;
        if (dt < n) {
            int t = t0 + dt;
            int row = obs[t] * NBLK + i;
            int col = obs[t + 1] * NBLK;
            const float4* src = reinterpret_cast<const float4*>(T + (size_t)row * NSTATES + col);
            float4 v0 = src[0], v1 = src[1];
            float vv[8] = {v0.x, v0.y, v0.z, v0.w, v1.x, v1.y, v1.z, v1.w};
            float* base = &sM[dt * 64 + i];            // [dt*64 + col*8 + row]
#pragma unroll
            for (int j = 0; j < 8; ++j) base[j * 8] = vv[j];
        }
        if (tid < CHK) sObs[tid] = obs[t0 + tid];
    }
    __syncthreads();

    if (tid >= 64) {
        // ---- fill waves (1-3): zero own rows, channel-phase-rotated -------
        float* p = out + (size_t)131072 * b + 1;       // own 512KiB region
        int wt = tid - 64;
        if (wt < 3) p[wt] = 0.f;                       // head: row 32b cols 0..2
        if (wt == 3) p[131071] = 0.f;                  // tail: row 32b+31 col 4095
        float4* b4 = reinterpret_cast<float4*>(p + 3); // 32767 float4s
        const int ROT = b * 128;                       // 2KiB phase per block
        const float4 z = make_float4(0.f, 0.f, 0.f, 0.f);
#pragma unroll 4
        for (int idx = wt; idx < 32767; idx += 192) {
            int ir = idx + ROT;
            if (ir >= 32767) ir -= 32767;
            b4[ir] = z;
        }
    } else {
        // ================= wave 0: the scan chain ==========================
        const int i = tid >> 3, j = tid & 7;
        // ---- chunk product: lane (i,j) holds P[i][j] ----
        {
            float p = sM[j * 8 + i];
            float m[8], mn[8];
#pragma unroll
            for (int k = 0; k < 8; ++k) m[k] = sM[64 + j * 8 + k];
            for (int dt = 1; dt < n; ++dt) {
                int dtn = min(dt + 1, n - 1);
#pragma unroll
                for (int k = 0; k < 8; ++k) mn[k] = sM[dtn * 64 + j * 8 + k];
                float pn = 0.f;
#pragma unroll
                for (int k = 0; k < 8; ++k) pn = fmaf(__shfl(p, i * 8 + k, 64), m[k], pn);
                if ((dt & 3) == 0) pn = exp_renorm(pn, __shfl(pn, 0, 64));
                p = pn;
#pragma unroll
                for (int k = 0; k < 8; ++k) m[k] = mn[k];
            }
            p = exp_renorm(p, __shfl(p, 0, 64));
            astore(&ws[OFF_P + b * 64 + j * 8 + i], p);
        }
        VMFENCE();
        if (tid == 0) astoreu(&flg[FLG_F1 + b], MAGIC);

        // ---- group duty (blocks 0..15): product of group's 16 P's ----
        if (b < NGRP) {
            for (;;) {
                bool ok = true;
                if (tid < GSZ)
                    ok = aloadu(&flg[FLG_F1 + GSZ * b + tid]) == MAGIC;
                if (__all(ok)) break;
                __builtin_amdgcn_s_sleep(1);
            }
            // stage duty group's 16 P matrices into LDS (pipelined loads)
            for (int q = tid; q < GSZ * 64; q += 64)
                sDuty[q] = aload(&ws[OFF_P + (size_t)b * GSZ * 64 + q]);
            LDSFENCE();   // wave-local: writes visible to all lanes of wave 0
            float p = sDuty[j * 8 + i];
            float m[8], mn[8];
#pragma unroll
            for (int k = 0; k < 8; ++k) m[k] = sDuty[64 + j * 8 + k];
            for (int r = 1; r < GSZ; ++r) {
                int rn = min(r + 1, GSZ - 1);
#pragma unroll
                for (int k = 0; k < 8; ++k) mn[k] = sDuty[rn * 64 + j * 8 + k];
                float pn = 0.f;
#pragma unroll
                for (int k = 0; k < 8; ++k) pn = fmaf(__shfl(p, i * 8 + k, 64), m[k], pn);
                if ((r & 1) == 0 || r == GSZ - 1) pn = exp_renorm(pn, __shfl(pn, 0, 64));
                p = pn;
#pragma unroll
                for (int k = 0; k < 8; ++k) m[k] = mn[k];
            }
            astore(&ws[OFF_G2 + b * 64 + j * 8 + i], p);
            VMFENCE();
            if (tid == 0) astoreu(&flg[FLG_F2 + b], MAGIC);
        }

        // ---- wait for all 16 F2 (transitively covers all F1 payloads) ----
        for (;;) {
            bool ok = true;
            if (tid < NGRP)
                ok = aloadu(&flg[FLG_F2 + tid]) == MAGIC;
            if (__all(ok)) break;
            __builtin_amdgcn_s_sleep(1);
        }
        // ---- stage G2 (all 16) + own group's P into LDS ----
        for (int q = tid; q < NGRP * 64; q += 64) sG2[q] = aload(&ws[OFF_G2 + q]);
        for (int q = tid; q < GSZ * 64; q += 64)
            sGP[q] = aload(&ws[OFF_P + (size_t)g * GSZ * 64 + q]);
        LDSFENCE();

        if (tid < 16) {
            const int grp = tid >> 3, l8 = tid & 7;
            const int st = grp ? 8 : 1;
            const int boff = grp ? l8 : l8 * 8;
            // ---- redundant global dual scan over 16 group products ----
            float v[8], vb[8];
            {
                float a = Pi[obs[0] * NBLK + l8];
                float s0 = a;
                s0 += __shfl_xor(s0, 1); s0 += __shfl_xor(s0, 2); s0 += __shfl_xor(s0, 4);
                float rs0 = 1.0f / s0;
#pragma unroll
                for (int q = 0; q < 8; ++q) v[q] = grp ? 0.125f : __shfl(a, q, 8) * rs0;
                ll0 = __logf(s0);
            }
            const int cap = grp ? (NGRP - 1 - g) : g;
            if (cap == 0) {
#pragma unroll
                for (int q = 0; q < 8; ++q) vb[q] = v[q];
            }
            for (int r = 0; r < NGRP - 1; ++r) {
                int gi = grp ? (NGRP - 1 - r) : r;
                const float* mb = &sG2[gi * 64 + boff];
                float m[8];
#pragma unroll
                for (int q = 0; q < 8; ++q) m[q] = mb[q * st];
                float u = 0.f;
#pragma unroll
                for (int q = 0; q < 8; ++q) u = fmaf(v[q], m[q], u);
                float s = 0.f;
#pragma unroll
                for (int q = 0; q < 8; ++q) { float x = __shfl(u, q, 8); v[q] = x; s += x; }
                float rs = 1.0f / s;
#pragma unroll
                for (int q = 0; q < 8; ++q) v[q] *= rs;
                if (r + 1 == cap) {
#pragma unroll
                    for (int q = 0; q < 8; ++q) vb[q] = v[q];
                }
            }
            // ---- predicated advance to own chunk boundary (<=15 steps) ----
#pragma unroll
            for (int q = 0; q < 8; ++q) v[q] = vb[q];
            const int cnt = grp ? (GSZ - 1 - rIn) : rIn;
            for (int q = 0; q < GSZ - 1; ++q) {
                bool act = q < cnt;
                int qc = act ? q : 0;
                int lc = grp ? (GSZ - 1 - qc) : qc;
                const float* mb = &sGP[lc * 64 + boff];
                float m[8];
#pragma unroll
                for (int k = 0; k < 8; ++k) m[k] = mb[k * st];
                float u = 0.f;
#pragma unroll
                for (int k = 0; k < 8; ++k) u = fmaf(v[k], m[k], u);
                float s = 0.f;
                float vn[8];
#pragma unroll
                for (int k = 0; k < 8; ++k) { float x = __shfl(u, k, 8); vn[k] = x; s += x; }
                float rs = 1.0f / s;
#pragma unroll
                for (int k = 0; k < 8; ++k) v[k] = act ? vn[k] * rs : v[k];
            }
            // ---- within-chunk dual rescan from sM ----
            float* hist = grp ? sB : sA;
            hist[(grp ? n : 0) * 8 + l8] = v[l8];
            int mt0 = grp ? (n - 1) : 0;
            float m[8], mn[8];
#pragma unroll
            for (int q = 0; q < 8; ++q) m[q] = sM[mt0 * 64 + boff + q * st];
            float ll = 0.f;
            for (int rr = 0; rr < n; ++rr) {
                int rn2 = min(rr + 1, n - 1);
                int mtn = grp ? (n - 1 - rn2) : rn2;
#pragma unroll
                for (int q = 0; q < 8; ++q) mn[q] = sM[mtn * 64 + boff + q * st];
                float u = 0.f;
#pragma unroll
                for (int q = 0; q < 8; ++q) u = fmaf(v[q], m[q], u);
                float s = 0.f;
#pragma unroll
                for (int q = 0; q < 8; ++q) { float x = __shfl(u, q, 8); v[q] = x; s += x; }
                float rs = 1.0f / s;
#pragma unroll
                for (int q = 0; q < 8; ++q) v[q] *= rs;
                hist[(grp ? (n - 1 - rr) : (rr + 1)) * 8 + l8] = v[l8];
                ll += __logf(s);
#pragma unroll
                for (int q = 0; q < 8; ++q) m[q] = mn[q];
            }
            if (tid == 0) astore(&ws[OFF_LLP + b], ll);
        }
        VMFENCE();
        if (tid == 0) astoreu(&flg[FLG_F3 + b], MAGIC);
    }
    __syncthreads();   // join fill + scan; own rows are zeroed, sA/sB ready

    // ---- scatter gamma windows into own pre-zeroed rows (256 threads) -----
    {
        const int rr = tid >> 3, ii = tid & 7;
        float gp = sA[rr * 8 + ii] * sB[rr * 8 + ii];
        float gs = gp;
        gs += __shfl_xor(gs, 1); gs += __shfl_xor(gs, 2); gs += __shfl_xor(gs, 4);
        out[1 + (size_t)(t0 + rr) * NSTATES + sObs[rr] * NBLK + ii] = gp / gs;
    }

    // ---- block 0, wave 0: deterministic log-lik reduction -> out[0] -------
    if (b == 0 && tid < 64) {
        for (;;) {
            bool ok = true;
#pragma unroll
            for (int q = 0; q < 4; ++q)
                ok = ok && (aloadu(&flg[FLG_F3 + tid * 4 + q]) == MAGIC);
            if (__all(ok)) break;
            __builtin_amdgcn_s_sleep(1);
        }
        float part = 0.f;
#pragma unroll
        for (int q = 0; q < 4; ++q) part += aload(&ws[OFF_LLP + tid * 4 + q]);
        part += __shfl_xor(part, 32); part += __shfl_xor(part, 16);
        part += __shfl_xor(part, 8);  part += __shfl_xor(part, 4);
        part += __shfl_xor(part, 2);  part += __shfl_xor(part, 1);
        if (tid == 0) out[0] = part + ll0;
    }
}

extern "C" void kernel_launch(void* const* d_in, const int* in_sizes, int n_in,
                              void* d_out, int out_size, void* d_ws, size_t ws_size,
                              hipStream_t stream)
{
    const float* T   = (const float*)d_in[0];
    const float* Pi  = (const float*)d_in[1];
    const int*   obs = (const int*)d_in[2];
    float* out = (float*)d_out;
    float* ws  = (float*)d_ws;

    void* args[] = {(void*)&T, (void*)&Pi, (void*)&obs, (void*)&out, (void*)&ws};
    hipLaunchCooperativeKernel((const void*)kFB, dim3(NCH), dim3(256), args, 0, stream);
}

// Round 8
// 63.299 us; speedup vs baseline: 1.2300x; 1.2300x over previous
//
#include <hip/hip_runtime.h>

// CHMM forward-backward, clone-structured deterministic emission (n_clones=8).
// FB pass = length-8191 recurrence over 8-dim vectors. 3 REGULAR kernels
// (cooperative launch abandoned: its write path ran at 1.6-1.8 TB/s vs
// 7 TB/s for regular-launch fills on the same buffer).
//  K1 (256 blocks): gather per-step 8x8 T-blocks (echo row-major to ws) +
//      chunk products with power-of-2 renorm exponent tracking.
//  K2 (1 block, 16 waves): all-LDS hierarchical boundary scan (group
//      products -> dual group scan -> dual fill-in) + exact deterministic
//      log-lik (per-chunk log s_c + k_c*ln2, fixed tree) -> out[0].
//  K3 (256 blocks): dual within-chunk rescan + full-row streaming write
//      (pure float4 stores, uniform window per row; every byte written once).

#define NSTATES 4096
#define NBLK    8
#define LSEQ    8192
#define NSTEPS  8191
#define CHK     32
#define NCH     256
#define NGRP    16
#define GSZ     16

// ws float offsets
#define OFF_M   0u        // [NSTEPS*64] row-major per step: M[t*64 + i*8 + j]
#define OFF_P   524288u   // [NCH*64]  chunk products, col-major [c*64 + j*8 + i]
#define OFF_KE  540672u   // [NCH]     per-chunk renorm exponent (as float)
#define OFF_AB  540928u   // [NCH*8]   alpha at chunk starts (normalized)
#define OFF_BB  542976u   // [NCH*8]   beta at chunk ends (normalized)

__device__ __forceinline__ int expof(float x) {
    return (int)((__float_as_uint(x) >> 23) & 0xff) - 127;
}

// ---- K1: gather + chunk products -----------------------------------------
__global__ __launch_bounds__(256) void k1(const float* __restrict__ T,
                                          const int* __restrict__ obs,
                                          float* __restrict__ ws)
{
    __shared__ float sM[CHK * 64];   // col-major per step [dt*64 + j*8 + i]
    const int tid = threadIdx.x, b = blockIdx.x;
    const int t0 = b * CHK;
    const int n = min(CHK, NSTEPS - t0);   // 32; block 255: 31
    {
        int dt = tid >> 3, i = tid & 7;
        if (dt < n) {
            int t = t0 + dt;
            int row = obs[t] * NBLK + i;
            int col = obs[t + 1] * NBLK;
            const float4* src = reinterpret_cast<const float4*>(T + (size_t)row * NSTATES + col);
            float4 v0 = src[0], v1 = src[1];
            float4* gr = reinterpret_cast<float4*>(ws + OFF_M + (size_t)t * 64 + i * 8);
            gr[0] = v0; gr[1] = v1;               // row-major echo for K3
            float vv[8] = {v0.x, v0.y, v0.z, v0.w, v1.x, v1.y, v1.z, v1.w};
            float* base = &sM[dt * 64 + i];
#pragma unroll
            for (int j = 0; j < 8; ++j) base[j * 8] = vv[j];
        }
    }
    __syncthreads();
    if (tid < 64) {
        const int i = tid >> 3, j = tid & 7;
        float p = sM[j * 8 + i];
        int kTot = 0;
        float m[8], mn[8];
#pragma unroll
        for (int k = 0; k < 8; ++k) m[k] = sM[64 + j * 8 + k];
        for (int dt = 1; dt < n; ++dt) {
            int dtn = min(dt + 1, n - 1);
#pragma unroll
            for (int k = 0; k < 8; ++k) mn[k] = sM[dtn * 64 + j * 8 + k];
            float pn = 0.f;
#pragma unroll
            for (int k = 0; k < 8; ++k) pn = fmaf(__shfl(p, i * 8 + k, 64), m[k], pn);
            if ((dt & 3) == 0) {
                int ke = expof(__shfl(pn, 0, 64));
                pn = ldexpf(pn, -ke);
                kTot += ke;
            }
            p = pn;
#pragma unroll
            for (int k = 0; k < 8; ++k) m[k] = mn[k];
        }
        {
            int ke = expof(__shfl(p, 0, 64));
            p = ldexpf(p, -ke);
            kTot += ke;
        }
        ws[OFF_P + b * 64 + j * 8 + i] = p;       // col-major
        if (tid == 0) ws[OFF_KE + b] = (float)kTot;
    }
}

// ---- K2: boundary hierarchy + exact log-lik (1 block, 1024 threads) ------
__global__ __launch_bounds__(1024) void k2(const float* __restrict__ Pi,
                                           const int* __restrict__ obs,
                                           float* __restrict__ out,
                                           float* __restrict__ ws)
{
    __shared__ float sP[NCH * 64];               // 64 KB: all chunk products
    __shared__ float sG2[NGRP * 64];
    __shared__ float sAG[NGRP * 8], sBG[NGRP * 8];
    __shared__ float sAB[NCH * 8], sBB[NCH * 8];
    __shared__ float sKE[NCH];
    __shared__ float sLv[NCH + 1];               // [NCH] = log(c0)
    const int tid = threadIdx.x;
    const int w = tid >> 6, lane = tid & 63;
    {
        const float4* src = reinterpret_cast<const float4*>(ws + OFF_P);
        float4* dst = reinterpret_cast<float4*>(sP);
        for (int q = tid; q < NCH * 16; q += 1024) dst[q] = src[q];
        if (tid < NCH) sKE[tid] = ws[OFF_KE + tid];
    }
    __syncthreads();
    {   // group products: wave w handles group w, all from LDS
        const int i = lane >> 3, j = lane & 7;
        float p = sP[(GSZ * w) * 64 + j * 8 + i];
        float m[8], mn[8];
#pragma unroll
        for (int k = 0; k < 8; ++k) m[k] = sP[(GSZ * w + 1) * 64 + j * 8 + k];
        for (int r = 1; r < GSZ; ++r) {
            int rn = min(r + 1, GSZ - 1);
#pragma unroll
            for (int k = 0; k < 8; ++k) mn[k] = sP[(GSZ * w + rn) * 64 + j * 8 + k];
            float pn = 0.f;
#pragma unroll
            for (int k = 0; k < 8; ++k) pn = fmaf(__shfl(p, i * 8 + k, 64), m[k], pn);
            if ((r & 1) == 0 || r == GSZ - 1) pn = ldexpf(pn, -expof(__shfl(pn, 0, 64)));
            p = pn;
#pragma unroll
            for (int k = 0; k < 8; ++k) m[k] = mn[k];
        }
        sG2[w * 64 + j * 8 + i] = p;
    }
    __syncthreads();
    if (tid < 16) {   // dual group scan: fwd lanes 0-7, bwd lanes 8-15
        const int grp = tid >> 3, l8 = tid & 7;
        const int st = grp ? 8 : 1;
        const int boff = grp ? l8 : l8 * 8;
        float v[8];
        float a = Pi[obs[0] * NBLK + l8];
        float s0 = a;
        s0 += __shfl_xor(s0, 1); s0 += __shfl_xor(s0, 2); s0 += __shfl_xor(s0, 4);
        float rs0 = 1.0f / s0;
#pragma unroll
        for (int q = 0; q < 8; ++q) v[q] = grp ? 0.125f : __shfl(a, q, 8) * rs0;
        if (tid == 0) sLv[NCH] = __logf(s0);
        (grp ? &sBG[(NGRP - 1) * 8] : &sAG[0])[l8] = v[l8];
        for (int r = 0; r < NGRP - 1; ++r) {
            int gi = grp ? (NGRP - 1 - r) : r;
            const float* mb = &sG2[gi * 64 + boff];
            float m[8];
#pragma unroll
            for (int q = 0; q < 8; ++q) m[q] = mb[q * st];
            float u = 0.f;
#pragma unroll
            for (int q = 0; q < 8; ++q) u = fmaf(v[q], m[q], u);
            float s = 0.f;
#pragma unroll
            for (int q = 0; q < 8; ++q) { float x = __shfl(u, q, 8); v[q] = x; s += x; }
            float rs = 1.0f / s;
#pragma unroll
            for (int q = 0; q < 8; ++q) v[q] *= rs;
            (grp ? &sBG[(NGRP - 2 - r) * 8] : &sAG[(r + 1) * 8])[l8] = v[l8];
        }
    }
    __syncthreads();
    if (lane < 16) {   // fill-in: wave w, fwd lanes 0-7 / bwd lanes 8-15
        const int grp = lane >> 3, l8 = lane & 7;
        const int st = grp ? 8 : 1;
        const int boff = grp ? l8 : l8 * 8;
        float v[8];
#pragma unroll
        for (int q = 0; q < 8; ++q) v[q] = grp ? sBG[w * 8 + q] : sAG[w * 8 + q];
        (grp ? &sBB[(GSZ * w + GSZ - 1) * 8] : &sAB[(GSZ * w) * 8])[l8] = v[l8];
        for (int r = 0; r < GSZ - 1; ++r) {
            int c = grp ? (GSZ * w + GSZ - 1 - r) : (GSZ * w + r);
            const float* mb = &sP[c * 64 + boff];
            float m[8];
#pragma unroll
            for (int q = 0; q < 8; ++q) m[q] = mb[q * st];
            float u = 0.f;
#pragma unroll
            for (int q = 0; q < 8; ++q) u = fmaf(v[q], m[q], u);
            float s = 0.f;
#pragma unroll
            for (int q = 0; q < 8; ++q) { float x = __shfl(u, q, 8); v[q] = x; s += x; }
            float rs = 1.0f / s;
#pragma unroll
            for (int q = 0; q < 8; ++q) v[q] *= rs;
            (grp ? &sBB[(GSZ * w + GSZ - 2 - r) * 8] : &sAB[(GSZ * w + r + 1) * 8])[l8] = v[l8];
        }
    }
    __syncthreads();
    {   // per-chunk ll: 128 8-lane groups x 2 passes; s_c = sum(a_c P_c)
        const int gidx = tid >> 3, l8 = tid & 7;
#pragma unroll
        for (int pass = 0; pass < 2; ++pass) {
            int c = pass * 128 + gidx;
            float u = 0.f;
#pragma unroll
            for (int i2 = 0; i2 < 8; ++i2)
                u = fmaf(sAB[c * 8 + i2], sP[c * 64 + l8 * 8 + i2], u);
            float s = u;
            s += __shfl_xor(s, 1); s += __shfl_xor(s, 2); s += __shfl_xor(s, 4);
            if (l8 == 0) sLv[c] = __logf(s) + sKE[c] * 0.69314718055994531f;
        }
    }
    __syncthreads();
    {   // write AB/BB to ws
        float4* d1 = reinterpret_cast<float4*>(ws + OFF_AB);
        const float4* s1 = reinterpret_cast<const float4*>(sAB);
        for (int q = tid; q < NCH * 2; q += 1024) d1[q] = s1[q];
        float4* d2 = reinterpret_cast<float4*>(ws + OFF_BB);
        const float4* s2 = reinterpret_cast<const float4*>(sBB);
        for (int q = tid; q < NCH * 2; q += 1024) d2[q] = s2[q];
    }
    if (tid < 64) {   // deterministic fixed-tree reduce -> out[0]
        float part = 0.f;
#pragma unroll
        for (int q = 0; q < 4; ++q) part += sLv[tid * 4 + q];
        part += __shfl_xor(part, 32); part += __shfl_xor(part, 16);
        part += __shfl_xor(part, 8);  part += __shfl_xor(part, 4);
        part += __shfl_xor(part, 2);  part += __shfl_xor(part, 1);
        if (tid == 0) out[0] = part + sLv[NCH];
    }
}

// ---- K3: rescan + full-row streaming write -------------------------------
__global__ __launch_bounds__(256) void k3(const int* __restrict__ obs,
                                          float* __restrict__ out,
                                          float* __restrict__ ws)
{
    __shared__ float sMc[CHK * 64];              // col-major per step
    __shared__ float sA[(CHK + 1) * 8], sB[(CHK + 1) * 8];
    __shared__ float sGv[CHK * 8];
    __shared__ int   sW[CHK];
    const int tid = threadIdx.x, b = blockIdx.x;
    const int t0 = b * CHK;
    const int n = min(CHK, NSTEPS - t0);
    {   // stage row-major from ws, transpose into col-major LDS
        const float4* src = reinterpret_cast<const float4*>(ws + OFF_M + (size_t)t0 * 64);
        for (int q = tid; q < n * 16; q += 256) {
            float4 v = src[q];
            int dt = q >> 4, r = q & 15, i = r >> 1, c0 = (r & 1) * 4;
            sMc[dt * 64 + (c0 + 0) * 8 + i] = v.x;
            sMc[dt * 64 + (c0 + 1) * 8 + i] = v.y;
            sMc[dt * 64 + (c0 + 2) * 8 + i] = v.z;
            sMc[dt * 64 + (c0 + 3) * 8 + i] = v.w;
        }
        if (tid < CHK) sW[tid] = obs[t0 + tid] * NBLK;
    }
    __syncthreads();
    if (tid < 16) {   // dual rescan: fwd lanes 0-7, bwd lanes 8-15
        const int grp = tid >> 3, l8 = tid & 7;
        const int st = grp ? 8 : 1;
        const int boff = grp ? l8 : l8 * 8;
        float v[8];
#pragma unroll
        for (int q = 0; q < 8; ++q)
            v[q] = grp ? ws[OFF_BB + b * 8 + q] : ws[OFF_AB + b * 8 + q];
        float* hist = grp ? sB : sA;
        hist[(grp ? n : 0) * 8 + l8] = v[l8];
        int mt0 = grp ? (n - 1) : 0;
        float m[8], mn[8];
#pragma unroll
        for (int q = 0; q < 8; ++q) m[q] = sMc[mt0 * 64 + boff + q * st];
        for (int rr = 0; rr < n; ++rr) {
            int rn2 = min(rr + 1, n - 1);
            int mtn = grp ? (n - 1 - rn2) : rn2;
#pragma unroll
            for (int q = 0; q < 8; ++q) mn[q] = sMc[mtn * 64 + boff + q * st];
            float u = 0.f;
#pragma unroll
            for (int q = 0; q < 8; ++q) u = fmaf(v[q], m[q], u);
            float s = 0.f;
#pragma unroll
            for (int q = 0; q < 8; ++q) { float x = __shfl(u, q, 8); v[q] = x; s += x; }
            float rs = 1.0f / s;
#pragma unroll
            for (int q = 0; q < 8; ++q) v[q] *= rs;
            hist[(grp ? (n - 1 - rr) : (rr + 1)) * 8 + l8] = v[l8];
#pragma unroll
            for (int q = 0; q < 8; ++q) m[q] = mn[q];
        }
    }
    __syncthreads();
    {   // normalized gamma windows
        const int rr = tid >> 3, ii = tid & 7;
        float gp = sA[rr * 8 + ii] * sB[rr * 8 + ii];
        float gs = gp;
        gs += __shfl_xor(gs, 1); gs += __shfl_xor(gs, 2); gs += __shfl_xor(gs, 4);
        sGv[rr * 8 + ii] = gp / gs;
    }
    __syncthreads();
    {   // full-row stream: wave wv writes rows wv*8 .. wv*8+7 (write-once)
        const int wv = tid >> 6, lane = tid & 63;
        for (int rr = wv * 8; rr < wv * 8 + 8; ++rr) {
            const int t = t0 + rr;
            float* rp = out + 1 + (size_t)t * NSTATES;
            const int w8 = sW[rr];
            if (lane < 3) rp[lane] = (w8 == 0) ? sGv[rr * 8 + lane] : 0.f;
            if (lane == 3) rp[4095] = (w8 == 4088) ? sGv[rr * 8 + 7] : 0.f;
            float4* r4 = reinterpret_cast<float4*>(rp + 3);   // cols 3+4s..6+4s
#pragma unroll 4
            for (int s = lane; s < 1023; s += 64) {
                int col0 = 3 + 4 * s;
                float4 v = make_float4(0.f, 0.f, 0.f, 0.f);
                if (col0 + 3 >= w8 && col0 <= w8 + 7) {
#pragma unroll
                    for (int e = 0; e < 4; ++e) {
                        int d = col0 + e - w8;
                        if ((unsigned)d < 8u) (&v.x)[e] = sGv[rr * 8 + d];
                    }
                }
                r4[s] = v;
            }
        }
    }
}

extern "C" void kernel_launch(void* const* d_in, const int* in_sizes, int n_in,
                              void* d_out, int out_size, void* d_ws, size_t ws_size,
                              hipStream_t stream)
{
    const float* T   = (const float*)d_in[0];
    const float* Pi  = (const float*)d_in[1];
    const int*   obs = (const int*)d_in[2];
    float* out = (float*)d_out;
    float* ws  = (float*)d_ws;

    k1<<<NCH, 256, 0, stream>>>(T, obs, ws);
    k2<<<1, 1024, 0, stream>>>(Pi, obs, out, ws);
    k3<<<NCH, 256, 0, stream>>>(obs, out, ws);
}

// Round 9
// 56.733 us; speedup vs baseline: 1.3724x; 1.1157x over previous
//
#include <hip/hip_runtime.h>

// CHMM forward-backward, clone-structured deterministic emission (n_clones=8).
// SINGLE REGULAR-LAUNCH kernel (A/B vs R7: identical code, coop launch was
// the 1.6 TB/s write-path culprit theory). Point-to-point RELAXED agent-scope
// flag dataflow; 256 blocks x 256 threads co-resident by capacity (4 waves,
// 19KB LDS, low VGPR -> >=8 blocks/CU). Waves 1-3 of each block zero-fill
// that block's 32 output rows; wave 0 runs the chunked scan; __syncthreads
// joins; block scatters gamma windows into its own rows. Replays are
// value-idempotent -> stale flags safe.

#define NSTATES 4096
#define NBLK    8
#define LSEQ    8192
#define NSTEPS  8191
#define CHK     32
#define NCH     256
#define NGRP    16
#define GSZ     16

// ws float offsets
#define OFF_P   0u       // [NCH*64]  chunk products, col-major [c*64 + col*8 + row]
#define OFF_G2  16384u   // [NGRP*64] group products, col-major
#define OFF_LLP 17408u   // [NCH]     per-chunk log-lik partials
// ws uint offsets (flags)
#define FLG_F1  17664u   // [NCH]
#define FLG_F2  17920u   // [NGRP]
#define FLG_F3  17936u   // [NCH]
#define MAGIC   0x5A17C0DEu

__device__ __forceinline__ float aload(float* p) {
    return __hip_atomic_load(p, __ATOMIC_RELAXED, __HIP_MEMORY_SCOPE_AGENT);
}
__device__ __forceinline__ void astore(float* p, float v) {
    __hip_atomic_store(p, v, __ATOMIC_RELAXED, __HIP_MEMORY_SCOPE_AGENT);
}
__device__ __forceinline__ unsigned aloadu(unsigned* p) {
    return __hip_atomic_load(p, __ATOMIC_RELAXED, __HIP_MEMORY_SCOPE_AGENT);
}
__device__ __forceinline__ void astoreu(unsigned* p, unsigned v) {
    __hip_atomic_store(p, v, __ATOMIC_RELAXED, __HIP_MEMORY_SCOPE_AGENT);
}
#define VMFENCE()  asm volatile("s_waitcnt vmcnt(0)" ::: "memory")
#define LDSFENCE() asm volatile("s_waitcnt lgkmcnt(0)" ::: "memory")

__device__ __forceinline__ float exp_renorm(float x, float ref) {
    int k = (int)((__float_as_uint(ref) >> 23) & 0xff) - 127;
    return ldexpf(x, -k);
}

__global__ __launch_bounds__(256) void kFB(const float* __restrict__ T,
                                           const float* __restrict__ Pi,
                                           const int* __restrict__ obs,
                                           float* __restrict__ out,
                                           float* __restrict__ ws)
{
    __shared__ float sM[CHK * 64];        // own chunk matrices, col-major/step
    __shared__ float sDuty[GSZ * 64];     // duty group's chunk products (b<16)
    __shared__ float sG2[NGRP * 64];      // staged group products
    __shared__ float sGP[GSZ * 64];       // staged own-group chunk products
    __shared__ float sA[(CHK + 1) * 8];   // alpha history
    __shared__ float sB[(CHK + 1) * 8];   // beta history
    __shared__ int   sObs[CHK];
    unsigned* flg = reinterpret_cast<unsigned*>(ws);
    const int tid = threadIdx.x;
    const int b = blockIdx.x;
    const int g = b >> 4, rIn = b & 15;
    const int t0 = b * CHK;
    const int n = min(CHK, NSTEPS - t0);  // 32; block 255: 31
    float ll0 = 0.f;

    // ---- gather own chunk's 8x8 T-blocks into LDS (all 256 threads) -------
    {
        int dt = tid >> 3, i = tid & 7;
        if (dt < n) {
            int t = t0 + dt;
            int row = obs[t] * NBLK + i;
            int col = obs[t + 1] * NBLK;
            const float4* src = reinterpret_cast<const float4*>(T + (size_t)row * NSTATES + col);
            float4 v0 = src[0], v1 = src[1];
            float vv[8] = {v0.x, v0.y, v0.z, v0.w, v1.x, v1.y, v1.z, v1.w};
            float* base = &sM[dt * 64 + i];            // [dt*64 + col*8 + row]
#pragma unroll
            for (int j = 0; j < 8; ++j) base[j * 8] = vv[j];
        }
        if (tid < CHK) sObs[tid] = obs[t0 + tid];
    }
    __syncthreads();

    if (tid >= 64) {
        // ---- fill waves (1-3): zero own rows [32b, 32b+32) ----------------
        float* p = out + (size_t)131072 * b + 1;       // own 512KiB region
        int wt = tid - 64;
        if (wt < 3) p[wt] = 0.f;                       // head: row 32b cols 0..2
        if (wt == 3) p[131071] = 0.f;                  // tail: row 32b+31 col 4095
        float4* b4 = reinterpret_cast<float4*>(p + 3); // 32767 float4s
        const float4 z = make_float4(0.f, 0.f, 0.f, 0.f);
#pragma unroll 4
        for (int idx = wt; idx < 32767; idx += 192) b4[idx] = z;
    } else {
        // ================= wave 0: the scan chain ==========================
        const int i = tid >> 3, j = tid & 7;
        // ---- chunk product: lane (i,j) holds P[i][j] ----
        {
            float p = sM[j * 8 + i];
            float m[8], mn[8];
#pragma unroll
            for (int k = 0; k < 8; ++k) m[k] = sM[64 + j * 8 + k];
            for (int dt = 1; dt < n; ++dt) {
                int dtn = min(dt + 1, n - 1);
#pragma unroll
                for (int k = 0; k < 8; ++k) mn[k] = sM[dtn * 64 + j * 8 + k];
                float pn = 0.f;
#pragma unroll
                for (int k = 0; k < 8; ++k) pn = fmaf(__shfl(p, i * 8 + k, 64), m[k], pn);
                if ((dt & 3) == 0) pn = exp_renorm(pn, __shfl(pn, 0, 64));
                p = pn;
#pragma unroll
                for (int k = 0; k < 8; ++k) m[k] = mn[k];
            }
            p = exp_renorm(p, __shfl(p, 0, 64));
            astore(&ws[OFF_P + b * 64 + j * 8 + i], p);
        }
        VMFENCE();
        if (tid == 0) astoreu(&flg[FLG_F1 + b], MAGIC);

        // ---- group duty (blocks 0..15): product of group's 16 P's ----
        if (b < NGRP) {
            for (;;) {
                bool ok = true;
                if (tid < GSZ)
                    ok = aloadu(&flg[FLG_F1 + GSZ * b + tid]) == MAGIC;
                if (__all(ok)) break;
                __builtin_amdgcn_s_sleep(1);
            }
            // stage duty group's 16 P matrices into LDS (pipelined loads)
            for (int q = tid; q < GSZ * 64; q += 64)
                sDuty[q] = aload(&ws[OFF_P + (size_t)b * GSZ * 64 + q]);
            LDSFENCE();   // wave-local: writes visible to all lanes of wave 0
            float p = sDuty[j * 8 + i];
            float m[8], mn[8];
#pragma unroll
            for (int k = 0; k < 8; ++k) m[k] = sDuty[64 + j * 8 + k];
            for (int r = 1; r < GSZ; ++r) {
                int rn = min(r + 1, GSZ - 1);
#pragma unroll
                for (int k = 0; k < 8; ++k) mn[k] = sDuty[rn * 64 + j * 8 + k];
                float pn = 0.f;
#pragma unroll
                for (int k = 0; k < 8; ++k) pn = fmaf(__shfl(p, i * 8 + k, 64), m[k], pn);
                if ((r & 1) == 0 || r == GSZ - 1) pn = exp_renorm(pn, __shfl(pn, 0, 64));
                p = pn;
#pragma unroll
                for (int k = 0; k < 8; ++k) m[k] = mn[k];
            }
            astore(&ws[OFF_G2 + b * 64 + j * 8 + i], p);
            VMFENCE();
            if (tid == 0) astoreu(&flg[FLG_F2 + b], MAGIC);
        }

        // ---- wait for all 16 F2 (transitively covers all F1 payloads) ----
        for (;;) {
            bool ok = true;
            if (tid < NGRP)
                ok = aloadu(&flg[FLG_F2 + tid]) == MAGIC;
            if (__all(ok)) break;
            __builtin_amdgcn_s_sleep(1);
        }
        // ---- stage G2 (all 16) + own group's P into LDS ----
        for (int q = tid; q < NGRP * 64; q += 64) sG2[q] = aload(&ws[OFF_G2 + q]);
        for (int q = tid; q < GSZ * 64; q += 64)
            sGP[q] = aload(&ws[OFF_P + (size_t)g * GSZ * 64 + q]);
        LDSFENCE();

        if (tid < 16) {
            const int grp = tid >> 3, l8 = tid & 7;
            const int st = grp ? 8 : 1;
            const int boff = grp ? l8 : l8 * 8;
            // ---- redundant global dual scan over 16 group products ----
            float v[8], vb[8];
            {
                float a = Pi[obs[0] * NBLK + l8];
                float s0 = a;
                s0 += __shfl_xor(s0, 1); s0 += __shfl_xor(s0, 2); s0 += __shfl_xor(s0, 4);
                float rs0 = 1.0f / s0;
#pragma unroll
                for (int q = 0; q < 8; ++q) v[q] = grp ? 0.125f : __shfl(a, q, 8) * rs0;
                ll0 = __logf(s0);
            }
            const int cap = grp ? (NGRP - 1 - g) : g;
            if (cap == 0) {
#pragma unroll
                for (int q = 0; q < 8; ++q) vb[q] = v[q];
            }
            for (int r = 0; r < NGRP - 1; ++r) {
                int gi = grp ? (NGRP - 1 - r) : r;
                const float* mb = &sG2[gi * 64 + boff];
                float m[8];
#pragma unroll
                for (int q = 0; q < 8; ++q) m[q] = mb[q * st];
                float u = 0.f;
#pragma unroll
                for (int q = 0; q < 8; ++q) u = fmaf(v[q], m[q], u);
                float s = 0.f;
#pragma unroll
                for (int q = 0; q < 8; ++q) { float x = __shfl(u, q, 8); v[q] = x; s += x; }
                float rs = 1.0f / s;
#pragma unroll
                for (int q = 0; q < 8; ++q) v[q] *= rs;
                if (r + 1 == cap) {
#pragma unroll
                    for (int q = 0; q < 8; ++q) vb[q] = v[q];
                }
            }
            // ---- predicated advance to own chunk boundary (<=15 steps) ----
#pragma unroll
            for (int q = 0; q < 8; ++q) v[q] = vb[q];
            const int cnt = grp ? (GSZ - 1 - rIn) : rIn;
            for (int q = 0; q < GSZ - 1; ++q) {
                bool act = q < cnt;
                int qc = act ? q : 0;
                int lc = grp ? (GSZ - 1 - qc) : qc;
                const float* mb = &sGP[lc * 64 + boff];
                float m[8];
#pragma unroll
                for (int k = 0; k < 8; ++k) m[k] = mb[k * st];
                float u = 0.f;
#pragma unroll
                for (int k = 0; k < 8; ++k) u = fmaf(v[k], m[k], u);
                float s = 0.f;
                float vn[8];
#pragma unroll
                for (int k = 0; k < 8; ++k) { float x = __shfl(u, k, 8); vn[k] = x; s += x; }
                float rs = 1.0f / s;
#pragma unroll
                for (int k = 0; k < 8; ++k) v[k] = act ? vn[k] * rs : v[k];
            }
            // ---- within-chunk dual rescan from sM ----
            float* hist = grp ? sB : sA;
            hist[(grp ? n : 0) * 8 + l8] = v[l8];
            int mt0 = grp ? (n - 1) : 0;
            float m[8], mn[8];
#pragma unroll
            for (int q = 0; q < 8; ++q) m[q] = sM[mt0 * 64 + boff + q * st];
            float ll = 0.f;
            for (int rr = 0; rr < n; ++rr) {
                int rn2 = min(rr + 1, n - 1);
                int mtn = grp ? (n - 1 - rn2) : rn2;
#pragma unroll
                for (int q = 0; q < 8; ++q) mn[q] = sM[mtn * 64 + boff + q * st];
                float u = 0.f;
#pragma unroll
                for (int q = 0; q < 8; ++q) u = fmaf(v[q], m[q], u);
                float s = 0.f;
#pragma unroll
                for (int q = 0; q < 8; ++q) { float x = __shfl(u, q, 8); v[q] = x; s += x; }
                float rs = 1.0f / s;
#pragma unroll
                for (int q = 0; q < 8; ++q) v[q] *= rs;
                hist[(grp ? (n - 1 - rr) : (rr + 1)) * 8 + l8] = v[l8];
                ll += __logf(s);
#pragma unroll
                for (int q = 0; q < 8; ++q) m[q] = mn[q];
            }
            if (tid == 0) astore(&ws[OFF_LLP + b], ll);
        }
        VMFENCE();
        if (tid == 0) astoreu(&flg[FLG_F3 + b], MAGIC);
    }
    __syncthreads();   // join fill + scan; own rows are zeroed, sA/sB ready

    // ---- scatter gamma windows into own pre-zeroed rows (256 threads) -----
    {
        const int rr = tid >> 3, ii = tid & 7;
        float gp = sA[rr * 8 + ii] * sB[rr * 8 + ii];
        float gs = gp;
        gs += __shfl_xor(gs, 1); gs += __shfl_xor(gs, 2); gs += __shfl_xor(gs, 4);
        out[1 + (size_t)(t0 + rr) * NSTATES + sObs[rr] * NBLK + ii] = gp / gs;
    }

    // ---- block 0, wave 0: deterministic log-lik reduction -> out[0] -------
    if (b == 0 && tid < 64) {
        for (;;) {
            bool ok = true;
#pragma unroll
            for (int q = 0; q < 4; ++q)
                ok = ok && (aloadu(&flg[FLG_F3 + tid * 4 + q]) == MAGIC);
            if (__all(ok)) break;
            __builtin_amdgcn_s_sleep(1);
        }
        float part = 0.f;
#pragma unroll
        for (int q = 0; q < 4; ++q) part += aload(&ws[OFF_LLP + tid * 4 + q]);
        part += __shfl_xor(part, 32); part += __shfl_xor(part, 16);
        part += __shfl_xor(part, 8);  part += __shfl_xor(part, 4);
        part += __shfl_xor(part, 2);  part += __shfl_xor(part, 1);
        if (tid == 0) out[0] = part + ll0;
    }
}

extern "C" void kernel_launch(void* const* d_in, const int* in_sizes, int n_in,
                              void* d_out, int out_size, void* d_ws, size_t ws_size,
                              hipStream_t stream)
{
    const float* T   = (const float*)d_in[0];
    const float* Pi  = (const float*)d_in[1];
    const int*   obs = (const int*)d_in[2];
    float* out = (float*)d_out;
    float* ws  = (float*)d_ws;

    kFB<<<NCH, 256, 0, stream>>>(T, Pi, obs, out, ws);
}

// Round 10
// 56.174 us; speedup vs baseline: 1.3860x; 1.0100x over previous
//
#include <hip/hip_runtime.h>

// CHMM forward-backward, clone-structured deterministic emission (n_clones=8).
// Single regular-launch kernel, RELAXED agent-scope flag dataflow.
// R10 change (single variable vs R9): 256 -> 1024 threads/block. Wave 0 runs
// the chunked scan; waves 1-15 (960 lanes) zero-fill the block's 32 output
// rows -- 15 fill waves/CU instead of 3 (R9's fill ran ~2.6 TB/s; store
// saturation needs more waves, cf. rocclr fill at ~32 waves/CU = 6.9 TB/s).
// __syncthreads joins; block scatters gamma windows into its own rows.
// Replays are value-idempotent -> stale flags safe.

#define NSTATES 4096
#define NBLK    8
#define LSEQ    8192
#define NSTEPS  8191
#define CHK     32
#define NCH     256
#define NGRP    16
#define GSZ     16

// ws float offsets
#define OFF_P   0u       // [NCH*64]  chunk products, col-major [c*64 + col*8 + row]
#define OFF_G2  16384u   // [NGRP*64] group products, col-major
#define OFF_LLP 17408u   // [NCH]     per-chunk log-lik partials
// ws uint offsets (flags)
#define FLG_F1  17664u   // [NCH]
#define FLG_F2  17920u   // [NGRP]
#define FLG_F3  17936u   // [NCH]
#define MAGIC   0x5A17C0DEu

__device__ __forceinline__ float aload(float* p) {
    return __hip_atomic_load(p, __ATOMIC_RELAXED, __HIP_MEMORY_SCOPE_AGENT);
}
__device__ __forceinline__ void astore(float* p, float v) {
    __hip_atomic_store(p, v, __ATOMIC_RELAXED, __HIP_MEMORY_SCOPE_AGENT);
}
__device__ __forceinline__ unsigned aloadu(unsigned* p) {
    return __hip_atomic_load(p, __ATOMIC_RELAXED, __HIP_MEMORY_SCOPE_AGENT);
}
__device__ __forceinline__ void astoreu(unsigned* p, unsigned v) {
    __hip_atomic_store(p, v, __ATOMIC_RELAXED, __HIP_MEMORY_SCOPE_AGENT);
}
#define VMFENCE()  asm volatile("s_waitcnt vmcnt(0)" ::: "memory")
#define LDSFENCE() asm volatile("s_waitcnt lgkmcnt(0)" ::: "memory")

__device__ __forceinline__ float exp_renorm(float x, float ref) {
    int k = (int)((__float_as_uint(ref) >> 23) & 0xff) - 127;
    return ldexpf(x, -k);
}

__global__ __launch_bounds__(1024) void kFB(const float* __restrict__ T,
                                            const float* __restrict__ Pi,
                                            const int* __restrict__ obs,
                                            float* __restrict__ out,
                                            float* __restrict__ ws)
{
    __shared__ float sM[CHK * 64];        // own chunk matrices, col-major/step
    __shared__ float sDuty[GSZ * 64];     // duty group's chunk products (b<16)
    __shared__ float sG2[NGRP * 64];      // staged group products
    __shared__ float sGP[GSZ * 64];       // staged own-group chunk products
    __shared__ float sA[(CHK + 1) * 8];   // alpha history
    __shared__ float sB[(CHK + 1) * 8];   // beta history
    __shared__ int   sObs[CHK];
    unsigned* flg = reinterpret_cast<unsigned*>(ws);
    const int tid = threadIdx.x;
    const int b = blockIdx.x;
    const int g = b >> 4, rIn = b & 15;
    const int t0 = b * CHK;
    const int n = min(CHK, NSTEPS - t0);  // 32; block 255: 31
    float ll0 = 0.f;

    // ---- gather own chunk's 8x8 T-blocks into LDS (lanes with dt<n) -------
    {
        int dt = tid >> 3, i = tid & 7;
        if (dt < n) {
            int t = t0 + dt;
            int row = obs[t] * NBLK + i;
            int col = obs[t + 1] * NBLK;
            const float4* src = reinterpret_cast<const float4*>(T + (size_t)row * NSTATES + col);
            float4 v0 = src[0], v1 = src[1];
            float vv[8] = {v0.x, v0.y, v0.z, v0.w, v1.x, v1.y, v1.z, v1.w};
            float* base = &sM[dt * 64 + i];            // [dt*64 + col*8 + row]
#pragma unroll
            for (int j = 0; j < 8; ++j) base[j * 8] = vv[j];
        }
        if (tid < CHK) sObs[tid] = obs[t0 + tid];
    }
    __syncthreads();

    if (tid >= 64) {
        // ---- fill waves (1-15): zero own rows [32b, 32b+32) ---------------
        float* p = out + (size_t)131072 * b + 1;       // own 512KiB region
        int wt = tid - 64;                             // 0..959
        if (wt < 3) p[wt] = 0.f;                       // head: row 32b cols 0..2
        if (wt == 3) p[131071] = 0.f;                  // tail: row 32b+31 col 4095
        float4* b4 = reinterpret_cast<float4*>(p + 3); // 32767 float4s
        const float4 z = make_float4(0.f, 0.f, 0.f, 0.f);
#pragma unroll 4
        for (int idx = wt; idx < 32767; idx += 960) b4[idx] = z;
    } else {
        // ================= wave 0: the scan chain ==========================
        const int i = tid >> 3, j = tid & 7;
        // ---- chunk product: lane (i,j) holds P[i][j] ----
        {
            float p = sM[j * 8 + i];
            float m[8], mn[8];
#pragma unroll
            for (int k = 0; k < 8; ++k) m[k] = sM[64 + j * 8 + k];
            for (int dt = 1; dt < n; ++dt) {
                int dtn = min(dt + 1, n - 1);
#pragma unroll
                for (int k = 0; k < 8; ++k) mn[k] = sM[dtn * 64 + j * 8 + k];
                float pn = 0.f;
#pragma unroll
                for (int k = 0; k < 8; ++k) pn = fmaf(__shfl(p, i * 8 + k, 64), m[k], pn);
                if ((dt & 3) == 0) pn = exp_renorm(pn, __shfl(pn, 0, 64));
                p = pn;
#pragma unroll
                for (int k = 0; k < 8; ++k) m[k] = mn[k];
            }
            p = exp_renorm(p, __shfl(p, 0, 64));
            astore(&ws[OFF_P + b * 64 + j * 8 + i], p);
        }
        VMFENCE();
        if (tid == 0) astoreu(&flg[FLG_F1 + b], MAGIC);

        // ---- group duty (blocks 0..15): product of group's 16 P's ----
        if (b < NGRP) {
            for (;;) {
                bool ok = true;
                if (tid < GSZ)
                    ok = aloadu(&flg[FLG_F1 + GSZ * b + tid]) == MAGIC;
                if (__all(ok)) break;
                __builtin_amdgcn_s_sleep(1);
            }
            // stage duty group's 16 P matrices into LDS (pipelined loads)
            for (int q = tid; q < GSZ * 64; q += 64)
                sDuty[q] = aload(&ws[OFF_P + (size_t)b * GSZ * 64 + q]);
            LDSFENCE();   // wave-local: writes visible to all lanes of wave 0
            float p = sDuty[j * 8 + i];
            float m[8], mn[8];
#pragma unroll
            for (int k = 0; k < 8; ++k) m[k] = sDuty[64 + j * 8 + k];
            for (int r = 1; r < GSZ; ++r) {
                int rn = min(r + 1, GSZ - 1);
#pragma unroll
                for (int k = 0; k < 8; ++k) mn[k] = sDuty[rn * 64 + j * 8 + k];
                float pn = 0.f;
#pragma unroll
                for (int k = 0; k < 8; ++k) pn = fmaf(__shfl(p, i * 8 + k, 64), m[k], pn);
                if ((r & 1) == 0 || r == GSZ - 1) pn = exp_renorm(pn, __shfl(pn, 0, 64));
                p = pn;
#pragma unroll
                for (int k = 0; k < 8; ++k) m[k] = mn[k];
            }
            astore(&ws[OFF_G2 + b * 64 + j * 8 + i], p);
            VMFENCE();
            if (tid == 0) astoreu(&flg[FLG_F2 + b], MAGIC);
        }

        // ---- wait for all 16 F2 (transitively covers all F1 payloads) ----
        for (;;) {
            bool ok = true;
            if (tid < NGRP)
                ok = aloadu(&flg[FLG_F2 + tid]) == MAGIC;
            if (__all(ok)) break;
            __builtin_amdgcn_s_sleep(1);
        }
        // ---- stage G2 (all 16) + own group's P into LDS ----
        for (int q = tid; q < NGRP * 64; q += 64) sG2[q] = aload(&ws[OFF_G2 + q]);
        for (int q = tid; q < GSZ * 64; q += 64)
            sGP[q] = aload(&ws[OFF_P + (size_t)g * GSZ * 64 + q]);
        LDSFENCE();

        if (tid < 16) {
            const int grp = tid >> 3, l8 = tid & 7;
            const int st = grp ? 8 : 1;
            const int boff = grp ? l8 : l8 * 8;
            // ---- redundant global dual scan over 16 group products ----
            float v[8], vb[8];
            {
                float a = Pi[obs[0] * NBLK + l8];
                float s0 = a;
                s0 += __shfl_xor(s0, 1); s0 += __shfl_xor(s0, 2); s0 += __shfl_xor(s0, 4);
                float rs0 = 1.0f / s0;
#pragma unroll
                for (int q = 0; q < 8; ++q) v[q] = grp ? 0.125f : __shfl(a, q, 8) * rs0;
                ll0 = __logf(s0);
            }
            const int cap = grp ? (NGRP - 1 - g) : g;
            if (cap == 0) {
#pragma unroll
                for (int q = 0; q < 8; ++q) vb[q] = v[q];
            }
            for (int r = 0; r < NGRP - 1; ++r) {
                int gi = grp ? (NGRP - 1 - r) : r;
                const float* mb = &sG2[gi * 64 + boff];
                float m[8];
#pragma unroll
                for (int q = 0; q < 8; ++q) m[q] = mb[q * st];
                float u = 0.f;
#pragma unroll
                for (int q = 0; q < 8; ++q) u = fmaf(v[q], m[q], u);
                float s = 0.f;
#pragma unroll
                for (int q = 0; q < 8; ++q) { float x = __shfl(u, q, 8); v[q] = x; s += x; }
                float rs = 1.0f / s;
#pragma unroll
                for (int q = 0; q < 8; ++q) v[q] *= rs;
                if (r + 1 == cap) {
#pragma unroll
                    for (int q = 0; q < 8; ++q) vb[q] = v[q];
                }
            }
            // ---- predicated advance to own chunk boundary (<=15 steps) ----
#pragma unroll
            for (int q = 0; q < 8; ++q) v[q] = vb[q];
            const int cnt = grp ? (GSZ - 1 - rIn) : rIn;
            for (int q = 0; q < GSZ - 1; ++q) {
                bool act = q < cnt;
                int qc = act ? q : 0;
                int lc = grp ? (GSZ - 1 - qc) : qc;
                const float* mb = &sGP[lc * 64 + boff];
                float m[8];
#pragma unroll
                for (int k = 0; k < 8; ++k) m[k] = mb[k * st];
                float u = 0.f;
#pragma unroll
                for (int k = 0; k < 8; ++k) u = fmaf(v[k], m[k], u);
                float s = 0.f;
                float vn[8];
#pragma unroll
                for (int k = 0; k < 8; ++k) { float x = __shfl(u, k, 8); vn[k] = x; s += x; }
                float rs = 1.0f / s;
#pragma unroll
                for (int k = 0; k < 8; ++k) v[k] = act ? vn[k] * rs : v[k];
            }
            // ---- within-chunk dual rescan from sM ----
            float* hist = grp ? sB : sA;
            hist[(grp ? n : 0) * 8 + l8] = v[l8];
            int mt0 = grp ? (n - 1) : 0;
            float m[8], mn[8];
#pragma unroll
            for (int q = 0; q < 8; ++q) m[q] = sM[mt0 * 64 + boff + q * st];
            float ll = 0.f;
            for (int rr = 0; rr < n; ++rr) {
                int rn2 = min(rr + 1, n - 1);
                int mtn = grp ? (n - 1 - rn2) : rn2;
#pragma unroll
                for (int q = 0; q < 8; ++q) mn[q] = sM[mtn * 64 + boff + q * st];
                float u = 0.f;
#pragma unroll
                for (int q = 0; q < 8; ++q) u = fmaf(v[q], m[q], u);
                float s = 0.f;
#pragma unroll
                for (int q = 0; q < 8; ++q) { float x = __shfl(u, q, 8); v[q] = x; s += x; }
                float rs = 1.0f / s;
#pragma unroll
                for (int q = 0; q < 8; ++q) v[q] *= rs;
                hist[(grp ? (n - 1 - rr) : (rr + 1)) * 8 + l8] = v[l8];
                ll += __logf(s);
#pragma unroll
                for (int q = 0; q < 8; ++q) m[q] = mn[q];
            }
            if (tid == 0) astore(&ws[OFF_LLP + b], ll);
        }
        VMFENCE();
        if (tid == 0) astoreu(&flg[FLG_F3 + b], MAGIC);
    }
    __syncthreads();   // join fill + scan; own rows are zeroed, sA/sB ready

    // ---- scatter gamma windows into own pre-zeroed rows (first 256) -------
    if (tid < 256) {
        const int rr = tid >> 3, ii = tid & 7;
        float gp = sA[rr * 8 + ii] * sB[rr * 8 + ii];
        float gs = gp;
        gs += __shfl_xor(gs, 1); gs += __shfl_xor(gs, 2); gs += __shfl_xor(gs, 4);
        out[1 + (size_t)(t0 + rr) * NSTATES + sObs[rr] * NBLK + ii] = gp / gs;
    }

    // ---- block 0, wave 0: deterministic log-lik reduction -> out[0] -------
    if (b == 0 && tid < 64) {
        for (;;) {
            bool ok = true;
#pragma unroll
            for (int q = 0; q < 4; ++q)
                ok = ok && (aloadu(&flg[FLG_F3 + tid * 4 + q]) == MAGIC);
            if (__all(ok)) break;
            __builtin_amdgcn_s_sleep(1);
        }
        float part = 0.f;
#pragma unroll
        for (int q = 0; q < 4; ++q) part += aload(&ws[OFF_LLP + tid * 4 + q]);
        part += __shfl_xor(part, 32); part += __shfl_xor(part, 16);
        part += __shfl_xor(part, 8);  part += __shfl_xor(part, 4);
        part += __shfl_xor(part, 2);  part += __shfl_xor(part, 1);
        if (tid == 0) out[0] = part + ll0;
    }
}

extern "C" void kernel_launch(void* const* d_in, const int* in_sizes, int n_in,
                              void* d_out, int out_size, void* d_ws, size_t ws_size,
                              hipStream_t stream)
{
    const float* T   = (const float*)d_in[0];
    const float* Pi  = (const float*)d_in[1];
    const int*   obs = (const int*)d_in[2];
    float* out = (float*)d_out;
    float* ws  = (float*)d_ws;

    kFB<<<NCH, 1024, 0, stream>>>(T, Pi, obs, out, ws);
}

// Round 11
// 54.783 us; speedup vs baseline: 1.4212x; 1.0254x over previous
//
#include <hip/hip_runtime.h>

// CHMM forward-backward, clone-structured deterministic emission (n_clones=8).
// Single regular-launch kernel, 512 blocks x 256 threads, RELAXED agent-scope
// flag dataflow. DECOUPLED: blocks 0..255 = scan-only (wave 0, no barriers,
// publishes compact gamma G to ws + F3); blocks 256..511 = fill-only (zero own
// 32 output rows, then poll F3[chunk], scatter windows from G). Removes the
// R10 barrier coupling (fill waves no longer held by wave0's cross-block
// chain) and keeps scan-side flag/stage ops off store-saturated CUs' queues.
// Replays are value-idempotent -> stale flags safe.

#define NSTATES 4096
#define NBLK    8
#define LSEQ    8192
#define NSTEPS  8191
#define CHK     32
#define NCH     256
#define NGRP    16
#define GSZ     16

// ws float offsets
#define OFF_P   0u       // [NCH*64]  chunk products, col-major [c*64 + col*8 + row]
#define OFF_G2  16384u   // [NGRP*64] group products, col-major
#define OFF_LLP 17408u   // [NCH]     per-chunk log-lik partials
#define OFF_G   18432u   // [LSEQ*8]  compact normalized gamma
// ws uint offsets (flags)
#define FLG_F1  17664u   // [NCH]
#define FLG_F2  17920u   // [NGRP]
#define FLG_F3  17936u   // [NCH]
#define MAGIC   0x5A17C0DEu

__device__ __forceinline__ float aload(float* p) {
    return __hip_atomic_load(p, __ATOMIC_RELAXED, __HIP_MEMORY_SCOPE_AGENT);
}
__device__ __forceinline__ void astore(float* p, float v) {
    __hip_atomic_store(p, v, __ATOMIC_RELAXED, __HIP_MEMORY_SCOPE_AGENT);
}
__device__ __forceinline__ unsigned aloadu(unsigned* p) {
    return __hip_atomic_load(p, __ATOMIC_RELAXED, __HIP_MEMORY_SCOPE_AGENT);
}
__device__ __forceinline__ void astoreu(unsigned* p, unsigned v) {
    __hip_atomic_store(p, v, __ATOMIC_RELAXED, __HIP_MEMORY_SCOPE_AGENT);
}
#define VMFENCE()  asm volatile("s_waitcnt vmcnt(0)" ::: "memory")
#define LDSFENCE() asm volatile("s_waitcnt lgkmcnt(0)" ::: "memory")

__device__ __forceinline__ float exp_renorm(float x, float ref) {
    int k = (int)((__float_as_uint(ref) >> 23) & 0xff) - 127;
    return ldexpf(x, -k);
}

__global__ __launch_bounds__(256) void kFB(const float* __restrict__ T,
                                           const float* __restrict__ Pi,
                                           const int* __restrict__ obs,
                                           float* __restrict__ out,
                                           float* __restrict__ ws)
{
    __shared__ float sM[CHK * 64];        // scan: chunk matrices, col-major/step
    __shared__ float sDuty[GSZ * 64];
    __shared__ float sG2[NGRP * 64];
    __shared__ float sGP[GSZ * 64];
    __shared__ float sA[(CHK + 1) * 8];
    __shared__ float sB[(CHK + 1) * 8];
    unsigned* flg = reinterpret_cast<unsigned*>(ws);
    const int tid = threadIdx.x;
    const int blk = blockIdx.x;

    if (blk >= NCH) {
        // ================= fill block: chunk c = blk - NCH =================
        const int c = blk - NCH;
        const int t0 = c * CHK;
        float* p = out + (size_t)131072 * c + 1;       // own 512KiB region
        if (tid < 3) p[tid] = 0.f;                     // head: row cols 0..2
        if (tid == 3) p[131071] = 0.f;                 // tail: last col
        float4* b4 = reinterpret_cast<float4*>(p + 3); // 32767 float4s
        const float4 z = make_float4(0.f, 0.f, 0.f, 0.f);
#pragma unroll 4
        for (int idx = tid; idx < 32767; idx += 256) b4[idx] = z;
        __syncthreads();                               // zeros drained (vmcnt)
        if (tid == 0) {
            while (aloadu(&flg[FLG_F3 + c]) != MAGIC) __builtin_amdgcn_s_sleep(8);
        }
        __syncthreads();                               // flag seen by all
        // scatter: lane (rr,ii) writes gamma[t0+rr][obs*8+ii]
        const int rr = tid >> 3, ii = tid & 7;
        int ob = obs[t0 + rr];
        float gv = aload(&ws[OFF_G + (size_t)(t0 + rr) * 8 + ii]);
        out[1 + (size_t)(t0 + rr) * NSTATES + ob * NBLK + ii] = gv;
        return;
    }

    // ==================== scan block (wave 0 only) =========================
    if (tid >= 64) return;
    const int b = blk;
    const int g = b >> 4, rIn = b & 15;
    const int t0 = b * CHK;
    const int n = min(CHK, NSTEPS - t0);  // 32; block 255: 31
    float ll0 = 0.f;
    const int i = tid >> 3, j = tid & 7;

    // ---- gather own chunk's 8x8 T-blocks into LDS (64 lanes, 4 iters) -----
    for (int u = tid; u < n * 8; u += 64) {
        int dt = u >> 3, ri = u & 7;
        int t = t0 + dt;
        int row = obs[t] * NBLK + ri;
        int col = obs[t + 1] * NBLK;
        const float4* src = reinterpret_cast<const float4*>(T + (size_t)row * NSTATES + col);
        float4 v0 = src[0], v1 = src[1];
        float vv[8] = {v0.x, v0.y, v0.z, v0.w, v1.x, v1.y, v1.z, v1.w};
        float* base = &sM[dt * 64 + ri];               // [dt*64 + col*8 + row]
#pragma unroll
        for (int jj = 0; jj < 8; ++jj) base[jj * 8] = vv[jj];
    }
    LDSFENCE();

    // ---- chunk product: lane (i,j) holds P[i][j] ----
    {
        float p = sM[j * 8 + i];
        float m[8], mn[8];
#pragma unroll
        for (int k = 0; k < 8; ++k) m[k] = sM[64 + j * 8 + k];
        for (int dt = 1; dt < n; ++dt) {
            int dtn = min(dt + 1, n - 1);
#pragma unroll
            for (int k = 0; k < 8; ++k) mn[k] = sM[dtn * 64 + j * 8 + k];
            float pn = 0.f;
#pragma unroll
            for (int k = 0; k < 8; ++k) pn = fmaf(__shfl(p, i * 8 + k, 64), m[k], pn);
            if ((dt & 3) == 0) pn = exp_renorm(pn, __shfl(pn, 0, 64));
            p = pn;
#pragma unroll
            for (int k = 0; k < 8; ++k) m[k] = mn[k];
        }
        p = exp_renorm(p, __shfl(p, 0, 64));
        astore(&ws[OFF_P + b * 64 + j * 8 + i], p);
    }
    VMFENCE();
    if (tid == 0) astoreu(&flg[FLG_F1 + b], MAGIC);

    // ---- group duty (blocks 0..15): product of group's 16 P's ----
    if (b < NGRP) {
        for (;;) {
            bool ok = true;
            if (tid < GSZ)
                ok = aloadu(&flg[FLG_F1 + GSZ * b + tid]) == MAGIC;
            if (__all(ok)) break;
            __builtin_amdgcn_s_sleep(1);
        }
        for (int q = tid; q < GSZ * 64; q += 64)
            sDuty[q] = aload(&ws[OFF_P + (size_t)b * GSZ * 64 + q]);
        LDSFENCE();
        float p = sDuty[j * 8 + i];
        float m[8], mn[8];
#pragma unroll
        for (int k = 0; k < 8; ++k) m[k] = sDuty[64 + j * 8 + k];
        for (int r = 1; r < GSZ; ++r) {
            int rn = min(r + 1, GSZ - 1);
#pragma unroll
            for (int k = 0; k < 8; ++k) mn[k] = sDuty[rn * 64 + j * 8 + k];
            float pn = 0.f;
#pragma unroll
            for (int k = 0; k < 8; ++k) pn = fmaf(__shfl(p, i * 8 + k, 64), m[k], pn);
            if ((r & 1) == 0 || r == GSZ - 1) pn = exp_renorm(pn, __shfl(pn, 0, 64));
            p = pn;
#pragma unroll
            for (int k = 0; k < 8; ++k) m[k] = mn[k];
        }
        astore(&ws[OFF_G2 + b * 64 + j * 8 + i], p);
        VMFENCE();
        if (tid == 0) astoreu(&flg[FLG_F2 + b], MAGIC);
    }

    // ---- wait for all 16 F2 (transitively covers all F1 payloads) ----
    for (;;) {
        bool ok = true;
        if (tid < NGRP)
            ok = aloadu(&flg[FLG_F2 + tid]) == MAGIC;
        if (__all(ok)) break;
        __builtin_amdgcn_s_sleep(1);
    }
    for (int q = tid; q < NGRP * 64; q += 64) sG2[q] = aload(&ws[OFF_G2 + q]);
    for (int q = tid; q < GSZ * 64; q += 64)
        sGP[q] = aload(&ws[OFF_P + (size_t)g * GSZ * 64 + q]);
    LDSFENCE();

    if (tid < 16) {
        const int grp = tid >> 3, l8 = tid & 7;
        const int st = grp ? 8 : 1;
        const int boff = grp ? l8 : l8 * 8;
        // ---- redundant global dual scan over 16 group products ----
        float v[8], vb[8];
        {
            float a = Pi[obs[0] * NBLK + l8];
            float s0 = a;
            s0 += __shfl_xor(s0, 1); s0 += __shfl_xor(s0, 2); s0 += __shfl_xor(s0, 4);
            float rs0 = 1.0f / s0;
#pragma unroll
            for (int q = 0; q < 8; ++q) v[q] = grp ? 0.125f : __shfl(a, q, 8) * rs0;
            ll0 = __logf(s0);
        }
        const int cap = grp ? (NGRP - 1 - g) : g;
        if (cap == 0) {
#pragma unroll
            for (int q = 0; q < 8; ++q) vb[q] = v[q];
        }
        for (int r = 0; r < NGRP - 1; ++r) {
            int gi = grp ? (NGRP - 1 - r) : r;
            const float* mb = &sG2[gi * 64 + boff];
            float m[8];
#pragma unroll
            for (int q = 0; q < 8; ++q) m[q] = mb[q * st];
            float u = 0.f;
#pragma unroll
            for (int q = 0; q < 8; ++q) u = fmaf(v[q], m[q], u);
            float s = 0.f;
#pragma unroll
            for (int q = 0; q < 8; ++q) { float x = __shfl(u, q, 8); v[q] = x; s += x; }
            float rs = 1.0f / s;
#pragma unroll
            for (int q = 0; q < 8; ++q) v[q] *= rs;
            if (r + 1 == cap) {
#pragma unroll
                for (int q = 0; q < 8; ++q) vb[q] = v[q];
            }
        }
        // ---- predicated advance to own chunk boundary (<=15 steps) ----
#pragma unroll
        for (int q = 0; q < 8; ++q) v[q] = vb[q];
        const int cnt = grp ? (GSZ - 1 - rIn) : rIn;
        for (int q = 0; q < GSZ - 1; ++q) {
            bool act = q < cnt;
            int qc = act ? q : 0;
            int lc = grp ? (GSZ - 1 - qc) : qc;
            const float* mb = &sGP[lc * 64 + boff];
            float m[8];
#pragma unroll
            for (int k = 0; k < 8; ++k) m[k] = mb[k * st];
            float u = 0.f;
#pragma unroll
            for (int k = 0; k < 8; ++k) u = fmaf(v[k], m[k], u);
            float s = 0.f;
            float vn[8];
#pragma unroll
            for (int k = 0; k < 8; ++k) { float x = __shfl(u, k, 8); vn[k] = x; s += x; }
            float rs = 1.0f / s;
#pragma unroll
            for (int k = 0; k < 8; ++k) v[k] = act ? vn[k] * rs : v[k];
        }
        // ---- within-chunk dual rescan from sM ----
        float* hist = grp ? sB : sA;
        hist[(grp ? n : 0) * 8 + l8] = v[l8];
        int mt0 = grp ? (n - 1) : 0;
        float m[8], mn[8];
#pragma unroll
        for (int q = 0; q < 8; ++q) m[q] = sM[mt0 * 64 + boff + q * st];
        float ll = 0.f;
        for (int rr = 0; rr < n; ++rr) {
            int rn2 = min(rr + 1, n - 1);
            int mtn = grp ? (n - 1 - rn2) : rn2;
#pragma unroll
            for (int q = 0; q < 8; ++q) mn[q] = sM[mtn * 64 + boff + q * st];
            float u = 0.f;
#pragma unroll
            for (int q = 0; q < 8; ++q) u = fmaf(v[q], m[q], u);
            float s = 0.f;
#pragma unroll
            for (int q = 0; q < 8; ++q) { float x = __shfl(u, q, 8); v[q] = x; s += x; }
            float rs = 1.0f / s;
#pragma unroll
            for (int q = 0; q < 8; ++q) v[q] *= rs;
            hist[(grp ? (n - 1 - rr) : (rr + 1)) * 8 + l8] = v[l8];
            ll += __logf(s);
#pragma unroll
            for (int q = 0; q < 8; ++q) m[q] = mn[q];
        }
        if (tid == 0) astore(&ws[OFF_LLP + b], ll);
    }
    LDSFENCE();   // sA/sB visible to all 64 lanes (single wave)

    // ---- publish compact normalized gamma G for this chunk ----------------
    {
        const int r0 = tid >> 3, ii = tid & 7;
#pragma unroll
        for (int k = 0; k < 4; ++k) {
            int rr = r0 + k * 8;
            float gp = sA[rr * 8 + ii] * sB[rr * 8 + ii];
            float gs = gp;
            gs += __shfl_xor(gs, 1); gs += __shfl_xor(gs, 2); gs += __shfl_xor(gs, 4);
            astore(&ws[OFF_G + (size_t)(t0 + rr) * 8 + ii], gp / gs);
        }
    }
    VMFENCE();
    if (tid == 0) astoreu(&flg[FLG_F3 + b], MAGIC);

    // ---- block 0: deterministic log-lik reduction -> out[0] ---------------
    if (b == 0) {
        for (;;) {
            bool ok = true;
#pragma unroll
            for (int q = 0; q < 4; ++q)
                ok = ok && (aloadu(&flg[FLG_F3 + tid * 4 + q]) == MAGIC);
            if (__all(ok)) break;
            __builtin_amdgcn_s_sleep(1);
        }
        float part = 0.f;
#pragma unroll
        for (int q = 0; q < 4; ++q) part += aload(&ws[OFF_LLP + tid * 4 + q]);
        part += __shfl_xor(part, 32); part += __shfl_xor(part, 16);
        part += __shfl_xor(part, 8);  part += __shfl_xor(part, 4);
        part += __shfl_xor(part, 2);  part += __shfl_xor(part, 1);
        if (tid == 0) out[0] = part + ll0;
    }
}

extern "C" void kernel_launch(void* const* d_in, const int* in_sizes, int n_in,
                              void* d_out, int out_size, void* d_ws, size_t ws_size,
                              hipStream_t stream)
{
    const float* T   = (const float*)d_in[0];
    const float* Pi  = (const float*)d_in[1];
    const int*   obs = (const int*)d_in[2];
    float* out = (float*)d_out;
    float* ws  = (float*)d_ws;

    kFB<<<NCH * 2, 256, 0, stream>>>(T, Pi, obs, out, ws);
}

// Round 12
// 41.864 us; speedup vs baseline: 1.8598x; 1.3086x over previous
//
#include <hip/hip_runtime.h>

// CHMM forward-backward, clone-structured deterministic emission (n_clones=8).
// Single regular-launch kernel, 512 blocks x 256 threads.
// NO fill<->scan ordering: output dwords are PARTITIONED by ownership derived
// from obs. Fill blocks (256..511) zero everything except each row's 8-float
// gamma window (straddled-float4 edges handled by explicit per-row rules) --
// pure streaming stores, zero flags/polls. Scan blocks (0..255) run the
// chunked scan hierarchy (relaxed agent-scope flags, ws only) and scatter
// exactly the window dwords: 3 scalars + 1 aligned float4 + 1 scalar per row.
// Every output byte has exactly one writer -> replay-safe by construction.
// out[0]=loglik written by scan block 0 after a fixed-tree reduce.

#define NSTATES 4096
#define NBLK    8
#define LSEQ    8192
#define NSTEPS  8191
#define CHK     32
#define NCH     256
#define NGRP    16
#define GSZ     16

// ws float offsets
#define OFF_P   0u       // [NCH*64]  chunk products, col-major [c*64 + col*8 + row]
#define OFF_G2  16384u   // [NGRP*64] group products, col-major
#define OFF_LLP 17408u   // [NCH]     per-chunk log-lik partials
// ws uint offsets (flags)
#define FLG_F1  17664u   // [NCH]
#define FLG_F2  17920u   // [NGRP]
#define FLG_F3  17936u   // [NCH]
#define MAGIC   0x5A17C0DEu

__device__ __forceinline__ float aload(float* p) {
    return __hip_atomic_load(p, __ATOMIC_RELAXED, __HIP_MEMORY_SCOPE_AGENT);
}
__device__ __forceinline__ void astore(float* p, float v) {
    __hip_atomic_store(p, v, __ATOMIC_RELAXED, __HIP_MEMORY_SCOPE_AGENT);
}
__device__ __forceinline__ unsigned aloadu(unsigned* p) {
    return __hip_atomic_load(p, __ATOMIC_RELAXED, __HIP_MEMORY_SCOPE_AGENT);
}
__device__ __forceinline__ void astoreu(unsigned* p, unsigned v) {
    __hip_atomic_store(p, v, __ATOMIC_RELAXED, __HIP_MEMORY_SCOPE_AGENT);
}
#define VMFENCE()  asm volatile("s_waitcnt vmcnt(0)" ::: "memory")
#define LDSFENCE() asm volatile("s_waitcnt lgkmcnt(0)" ::: "memory")

__device__ __forceinline__ float exp_renorm(float x, float ref) {
    int k = (int)((__float_as_uint(ref) >> 23) & 0xff) - 127;
    return ldexpf(x, -k);
}

__global__ __launch_bounds__(256) void kFB(const float* __restrict__ T,
                                           const float* __restrict__ Pi,
                                           const int* __restrict__ obs,
                                           float* __restrict__ out,
                                           float* __restrict__ ws)
{
    __shared__ float sM[CHK * 64];
    __shared__ float sDuty[GSZ * 64];
    __shared__ float sG2[NGRP * 64];
    __shared__ float sGP[GSZ * 64];
    __shared__ float sA[(CHK + 1) * 8];
    __shared__ float sB[(CHK + 1) * 8];
    __shared__ float sGv[CHK * 8];
    __shared__ int   sObs[CHK + 1];       // scan: obs[t0..t0+32]; fill: obs[r0-1..r0+31]
    unsigned* flg = reinterpret_cast<unsigned*>(ws);
    const int tid = threadIdx.x;
    const int blk = blockIdx.x;

    if (blk >= NCH) {
        // ============= FILL block: pure streaming zeros (no flags) =========
        const int c = blk - NCH;
        const int r0 = c * CHK;
        if (tid < CHK + 1) {
            int t = r0 - 1 + tid;
            sObs[tid] = (t >= 0) ? obs[t] : 0;   // sObs[0]=obs[r0-1], sObs[1+rr]=obs[r0+rr]
        }
        __syncthreads();
        float4* o4 = reinterpret_cast<float4*>(out);
        const float4 z = make_float4(0.f, 0.f, 0.f, 0.f);
        // main: per row rr, float4s k in [r*1024+1, (r+1)*1024), skip window k in {m,m+1,m+2}
#pragma unroll 2
        for (int q = tid; q < CHK * 1024; q += 256) {
            int rr = q >> 10, pos = q & 1023;
            int r = r0 + rr;
            int k = r * 1024 + pos;
            int m = r * 1024 + sObs[1 + rr] * 2;
            if (pos != 0 && (unsigned)(k - m) > 2u) o4[k] = z;
        }
        // specials: per row rr = tid>>3, role = tid&7
        {
            const int rr = tid >> 3, role = tid & 7;
            const int r = r0 + rr;
            const int ob = sObs[1 + rr];
            const int obPrev = sObs[rr];              // valid when r>0
            const int m = r * 1024 + ob * 2;
            const int ks = r * 1024;                  // straddler float4
            const bool fullStraddle = (r != 0) && (obPrev != 511) && (ob != 0);
            if (role == 0) {
                if (fullStraddle) o4[ks] = z;
                else if (r != 0 && obPrev != 511) out[(size_t)4 * ks] = 0.f;   // e0: prev row col 4095
            } else if (role <= 3) {
                if (!fullStraddle && ob != 0) out[(size_t)4 * ks + role] = 0.f; // e1-3: cols 0..2
            } else if (role <= 6) {
                if (ob <= 510) out[(size_t)4 * m + 9 + (role - 4)] = 0.f;       // cols w+8..w+10
            }
            if (tid == 255 && c == NCH - 1 && sObs[CHK] != 511)
                out[(size_t)LSEQ * NSTATES] = 0.f;    // trailing: row 8191 col 4095
        }
        return;
    }

    // ==================== SCAN block (wave 0 only) =========================
    if (tid >= 64) return;
    const int b = blk;
    const int g = b >> 4, rIn = b & 15;
    const int t0 = b * CHK;
    const int n = min(CHK, NSTEPS - t0);  // 32; block 255: 31
    float ll0 = 0.f;
    const int i = tid >> 3, j = tid & 7;

    // ---- gather own chunk's 8x8 T-blocks into LDS -------------------------
    for (int u = tid; u < n * 8; u += 64) {
        int dt = u >> 3, ri = u & 7;
        int t = t0 + dt;
        int row = obs[t] * NBLK + ri;
        int col = obs[t + 1] * NBLK;
        const float4* src = reinterpret_cast<const float4*>(T + (size_t)row * NSTATES + col);
        float4 v0 = src[0], v1 = src[1];
        float vv[8] = {v0.x, v0.y, v0.z, v0.w, v1.x, v1.y, v1.z, v1.w};
        float* base = &sM[dt * 64 + ri];               // [dt*64 + col*8 + row]
#pragma unroll
        for (int jj = 0; jj < 8; ++jj) base[jj * 8] = vv[jj];
    }
    if (tid < CHK) sObs[tid] = obs[t0 + tid];
    LDSFENCE();

    // ---- chunk product: lane (i,j) holds P[i][j] ----
    {
        float p = sM[j * 8 + i];
        float m[8], mn[8];
#pragma unroll
        for (int k = 0; k < 8; ++k) m[k] = sM[64 + j * 8 + k];
        for (int dt = 1; dt < n; ++dt) {
            int dtn = min(dt + 1, n - 1);
#pragma unroll
            for (int k = 0; k < 8; ++k) mn[k] = sM[dtn * 64 + j * 8 + k];
            float pn = 0.f;
#pragma unroll
            for (int k = 0; k < 8; ++k) pn = fmaf(__shfl(p, i * 8 + k, 64), m[k], pn);
            if ((dt & 3) == 0) pn = exp_renorm(pn, __shfl(pn, 0, 64));
            p = pn;
#pragma unroll
            for (int k = 0; k < 8; ++k) m[k] = mn[k];
        }
        p = exp_renorm(p, __shfl(p, 0, 64));
        astore(&ws[OFF_P + b * 64 + j * 8 + i], p);
    }
    VMFENCE();
    if (tid == 0) astoreu(&flg[FLG_F1 + b], MAGIC);

    // ---- group duty (blocks 0..15): product of group's 16 P's ----
    if (b < NGRP) {
        for (;;) {
            bool ok = true;
            if (tid < GSZ)
                ok = aloadu(&flg[FLG_F1 + GSZ * b + tid]) == MAGIC;
            if (__all(ok)) break;
            __builtin_amdgcn_s_sleep(1);
        }
        {   // pipelined register staging: 16 loads in flight
            float rb[16];
#pragma unroll
            for (int k = 0; k < 16; ++k)
                rb[k] = aload(&ws[OFF_P + (size_t)b * GSZ * 64 + k * 64 + tid]);
#pragma unroll
            for (int k = 0; k < 16; ++k) sDuty[k * 64 + tid] = rb[k];
        }
        LDSFENCE();
        float p = sDuty[j * 8 + i];
        float m[8], mn[8];
#pragma unroll
        for (int k = 0; k < 8; ++k) m[k] = sDuty[64 + j * 8 + k];
        for (int r = 1; r < GSZ; ++r) {
            int rn = min(r + 1, GSZ - 1);
#pragma unroll
            for (int k = 0; k < 8; ++k) mn[k] = sDuty[rn * 64 + j * 8 + k];
            float pn = 0.f;
#pragma unroll
            for (int k = 0; k < 8; ++k) pn = fmaf(__shfl(p, i * 8 + k, 64), m[k], pn);
            if ((r & 1) == 0 || r == GSZ - 1) pn = exp_renorm(pn, __shfl(pn, 0, 64));
            p = pn;
#pragma unroll
            for (int k = 0; k < 8; ++k) m[k] = mn[k];
        }
        astore(&ws[OFF_G2 + b * 64 + j * 8 + i], p);
        VMFENCE();
        if (tid == 0) astoreu(&flg[FLG_F2 + b], MAGIC);
    }

    // ---- wait for all 16 F2 (transitively covers all F1 payloads) ----
    for (;;) {
        bool ok = true;
        if (tid < NGRP)
            ok = aloadu(&flg[FLG_F2 + tid]) == MAGIC;
        if (__all(ok)) break;
        __builtin_amdgcn_s_sleep(1);
    }
    {   // pipelined staging of sG2 + own group's P (32 loads in flight)
        float ra[16], rb[16];
#pragma unroll
        for (int k = 0; k < 16; ++k) ra[k] = aload(&ws[OFF_G2 + k * 64 + tid]);
#pragma unroll
        for (int k = 0; k < 16; ++k)
            rb[k] = aload(&ws[OFF_P + (size_t)g * GSZ * 64 + k * 64 + tid]);
#pragma unroll
        for (int k = 0; k < 16; ++k) sG2[k * 64 + tid] = ra[k];
#pragma unroll
        for (int k = 0; k < 16; ++k) sGP[k * 64 + tid] = rb[k];
    }
    LDSFENCE();

    if (tid < 16) {
        const int grp = tid >> 3, l8 = tid & 7;
        const int st = grp ? 8 : 1;
        const int boff = grp ? l8 : l8 * 8;
        // ---- redundant global dual scan over 16 group products ----
        float v[8], vb[8];
        {
            float a = Pi[obs[0] * NBLK + l8];
            float s0 = a;
            s0 += __shfl_xor(s0, 1); s0 += __shfl_xor(s0, 2); s0 += __shfl_xor(s0, 4);
            float rs0 = 1.0f / s0;
#pragma unroll
            for (int q = 0; q < 8; ++q) v[q] = grp ? 0.125f : __shfl(a, q, 8) * rs0;
            ll0 = __logf(s0);
        }
        const int cap = grp ? (NGRP - 1 - g) : g;
        if (cap == 0) {
#pragma unroll
            for (int q = 0; q < 8; ++q) vb[q] = v[q];
        }
        for (int r = 0; r < NGRP - 1; ++r) {
            int gi = grp ? (NGRP - 1 - r) : r;
            const float* mb = &sG2[gi * 64 + boff];
            float m[8];
#pragma unroll
            for (int q = 0; q < 8; ++q) m[q] = mb[q * st];
            float u = 0.f;
#pragma unroll
            for (int q = 0; q < 8; ++q) u = fmaf(v[q], m[q], u);
            float s = 0.f;
#pragma unroll
            for (int q = 0; q < 8; ++q) { float x = __shfl(u, q, 8); v[q] = x; s += x; }
            float rs = 1.0f / s;
#pragma unroll
            for (int q = 0; q < 8; ++q) v[q] *= rs;
            if (r + 1 == cap) {
#pragma unroll
                for (int q = 0; q < 8; ++q) vb[q] = v[q];
            }
        }
        // ---- predicated advance to own chunk boundary (<=15 steps) ----
#pragma unroll
        for (int q = 0; q < 8; ++q) v[q] = vb[q];
        const int cnt = grp ? (GSZ - 1 - rIn) : rIn;
        for (int q = 0; q < GSZ - 1; ++q) {
            bool act = q < cnt;
            int qc = act ? q : 0;
            int lc = grp ? (GSZ - 1 - qc) : qc;
            const float* mb = &sGP[lc * 64 + boff];
            float m[8];
#pragma unroll
            for (int k = 0; k < 8; ++k) m[k] = mb[k * st];
            float u = 0.f;
#pragma unroll
            for (int k = 0; k < 8; ++k) u = fmaf(v[k], m[k], u);
            float s = 0.f;
            float vn[8];
#pragma unroll
            for (int k = 0; k < 8; ++k) { float x = __shfl(u, k, 8); vn[k] = x; s += x; }
            float rs = 1.0f / s;
#pragma unroll
            for (int k = 0; k < 8; ++k) v[k] = act ? vn[k] * rs : v[k];
        }
        // ---- within-chunk dual rescan from sM ----
        float* hist = grp ? sB : sA;
        hist[(grp ? n : 0) * 8 + l8] = v[l8];
        int mt0 = grp ? (n - 1) : 0;
        float m[8], mn[8];
#pragma unroll
        for (int q = 0; q < 8; ++q) m[q] = sM[mt0 * 64 + boff + q * st];
        float ll = 0.f;
        for (int rr = 0; rr < n; ++rr) {
            int rn2 = min(rr + 1, n - 1);
            int mtn = grp ? (n - 1 - rn2) : rn2;
#pragma unroll
            for (int q = 0; q < 8; ++q) mn[q] = sM[mtn * 64 + boff + q * st];
            float u = 0.f;
#pragma unroll
            for (int q = 0; q < 8; ++q) u = fmaf(v[q], m[q], u);
            float s = 0.f;
#pragma unroll
            for (int q = 0; q < 8; ++q) { float x = __shfl(u, q, 8); v[q] = x; s += x; }
            float rs = 1.0f / s;
#pragma unroll
            for (int q = 0; q < 8; ++q) v[q] *= rs;
            hist[(grp ? (n - 1 - rr) : (rr + 1)) * 8 + l8] = v[l8];
            ll += __logf(s);
#pragma unroll
            for (int q = 0; q < 8; ++q) m[q] = mn[q];
        }
        if (tid == 0) astore(&ws[OFF_LLP + b], ll);
    }
    LDSFENCE();   // sA/sB visible across wave 0

    // ---- normalized gamma -> sGv ------------------------------------------
    {
        const int r0l = tid >> 3, ii = tid & 7;
#pragma unroll
        for (int k = 0; k < 4; ++k) {
            int rr = r0l + k * 8;
            float gp = sA[rr * 8 + ii] * sB[rr * 8 + ii];
            float gs = gp;
            gs += __shfl_xor(gs, 1); gs += __shfl_xor(gs, 2); gs += __shfl_xor(gs, 4);
            sGv[rr * 8 + ii] = gp / gs;
        }
    }
    LDSFENCE();
    VMFENCE();
    if (tid == 0) astoreu(&flg[FLG_F3 + b], MAGIC);

    // ---- scatter: lane rr<32 writes row t0+rr's window dwords -------------
    if (tid < CHK) {
        const int r = t0 + tid;
        const int ob = sObs[tid];
        const size_t W = (size_t)r * NSTATES + ob * NBLK;   // gamma flat index
        const float* gv = &sGv[tid * 8];
        out[W + 1] = gv[0];
        out[W + 2] = gv[1];
        out[W + 3] = gv[2];
        reinterpret_cast<float4*>(out)[W / 4 + 1] = make_float4(gv[3], gv[4], gv[5], gv[6]);
        out[W + 8] = gv[7];
    }

    // ---- block 0: deterministic log-lik reduction -> out[0] ---------------
    if (b == 0) {
        for (;;) {
            bool ok = true;
#pragma unroll
            for (int q = 0; q < 4; ++q)
                ok = ok && (aloadu(&flg[FLG_F3 + tid * 4 + q]) == MAGIC);
            if (__all(ok)) break;
            __builtin_amdgcn_s_sleep(1);
        }
        float part = 0.f;
#pragma unroll
        for (int q = 0; q < 4; ++q) part += aload(&ws[OFF_LLP + tid * 4 + q]);
        part += __shfl_xor(part, 32); part += __shfl_xor(part, 16);
        part += __shfl_xor(part, 8);  part += __shfl_xor(part, 4);
        part += __shfl_xor(part, 2);  part += __shfl_xor(part, 1);
        if (tid == 0) out[0] = part + ll0;
    }
}

extern "C" void kernel_launch(void* const* d_in, const int* in_sizes, int n_in,
                              void* d_out, int out_size, void* d_ws, size_t ws_size,
                              hipStream_t stream)
{
    const float* T   = (const float*)d_in[0];
    const float* Pi  = (const float*)d_in[1];
    const int*   obs = (const int*)d_in[2];
    float* out = (float*)d_out;
    float* ws  = (float*)d_ws;

    kFB<<<NCH * 2, 256, 0, stream>>>(T, Pi, obs, out, ws);
}